// Round 1
// baseline (613.747 us; speedup 1.0000x reference)
//
#include <hip/hip_runtime.h>
#include <hip/hip_bf16.h>
#include <stdint.h>

// B=512, N=256, D=128, 4 layers, 1 head.
// One block per batch. Z (bf16) + keyT (bf16, transposed) + zbar (f32) in LDS.
// All 4 layers computed in-block; acc and R held in registers as packed bf16.

using short8 = __attribute__((ext_vector_type(8))) short;
using f32x4  = __attribute__((ext_vector_type(4))) float;

#define MFMA16(A, B, C) __builtin_amdgcn_mfma_f32_16x16x32_bf16((A), (B), (C), 0, 0, 0)

__device__ __forceinline__ uint16_t f2bf(float f) {
  __hip_bfloat16 h = __float2bfloat16(f);
  union { __hip_bfloat16 h; uint16_t u; } cv;
  cv.h = h;
  return cv.u;
}
__device__ __forceinline__ uint32_t pk2(float lo, float hi) {
  return (uint32_t)f2bf(lo) | ((uint32_t)f2bf(hi) << 16);
}
__device__ __forceinline__ float bflo(uint32_t p) { return __uint_as_float(p << 16); }
__device__ __forceinline__ float bfhi(uint32_t p) { return __uint_as_float(p & 0xffff0000u); }

// ---- LDS geometry (bytes) ----
#define ZP        136                        // Zbf pitch (elems): 272B rows -> 2-way bank alias only
#define KP        264                        // keyT pitch (elems): 528B rows
#define Z_BYTES   (272 * ZP * 2)             // 73,984
#define K_BYTES   (128 * KP * 2)             // 67,584
#define ZB_OFF    0
#define KT_OFF    Z_BYTES
#define ZBAR_OFF  (Z_BYTES + K_BYTES)        // 141,568
#define SCR_OFF   (ZBAR_OFF + 272 * 4)       // 142,656
#define SCRP      72                         // scratch pitch (elems): 144B rows
#define LDS_TOTAL (SCR_OFF + 8 * 16 * SCRP * 2)  // 161,088 <= 163,840

__global__ __launch_bounds__(512, 2)
void tf_layers(const float* __restrict__ Zin, const float* __restrict__ gamma,
               const uint16_t* __restrict__ Qtg, const uint16_t* __restrict__ Pg,
               float* __restrict__ Zout)
{
  extern __shared__ char lds[];
  uint16_t* Zbf  = (uint16_t*)(lds + ZB_OFF);    // [272][ZP] rows>=257 zero
  uint16_t* keyT = (uint16_t*)(lds + KT_OFF);    // [128][KP]  keyT[i][tok] = key[tok][i]
  float*    zbar = (float*)(lds + ZBAR_OFF);     // [272]      Z[:,128]

  const int tid  = threadIdx.x;
  const int lane = tid & 63;
  const int w    = tid >> 6;      // wave 0..7
  const int l15  = lane & 15;
  const int g    = lane >> 4;     // 0..3
  const int b    = blockIdx.x;

  uint16_t* scr = (uint16_t*)(lds + SCR_OFF) + w * 16 * SCRP;  // per-wave [16][SCRP]

  const float* Zb_in  = Zin  + (size_t)b * 33153;  // 257*129
  float*       Zb_out = Zout + (size_t)b * 33153;

  // ---- init: zero Zbf (incl. pad rows/cols), then fill rows<257 and zbar ----
  for (int k2 = tid; k2 < 272 * ZP; k2 += 512) Zbf[k2] = 0;
  __syncthreads();
  for (int k2 = tid; k2 < 33153; k2 += 512) {
    int r = k2 / 129, c = k2 - r * 129;
    float v = Zb_in[k2];
    if (c < 128) Zbf[r * ZP + c] = f2bf(v);
    else         zbar[r] = v;
  }

  const int ntile = (w == 0) ? 3 : 2;   // 17 row-tiles of 16 over 8 waves
  struct TS { uint32_t rpk[16]; float r128; uint32_t apk[16]; float a128; };
  TS ts[3];

  const float inv_n = 1.0f / 256.0f;

  for (int layer = 0; layer < 4; ++layer) {
    __syncthreads();  // init done / previous U done (Zbf, zbar stable)

    // ===== Phase K: keyT[i][tok] = sum_d Z[tok][d] * P[i][d]  (i-tile = w) =====
    {
      const uint16_t* Pl = Pg + layer * 16384;
      const int irow = 16 * w + l15;
      short8 bk[4];
      #pragma unroll
      for (int kk = 0; kk < 4; ++kk)
        bk[kk] = *(const short8*)(Pl + irow * 128 + kk * 32 + g * 8);
      #pragma unroll
      for (int t = 0; t < 16; ++t) {
        f32x4 acc = {0.f, 0.f, 0.f, 0.f};
        #pragma unroll
        for (int kk = 0; kk < 4; ++kk) {
          short8 az = *(const short8*)(Zbf + (16 * t + l15) * ZP + kk * 32 + g * 8);
          acc = MFMA16(az, bk[kk], acc);
        }
        // D[tok][i]: col=i=l15, rows tok=16t+4g+r -> pack pairs, write keyT[i][tok]
        uint32_t* dst = (uint32_t*)(keyT + irow * KP + 16 * t + 4 * g);
        dst[0] = pk2(acc[0], acc[1]);
        dst[1] = pk2(acc[2], acc[3]);
      }
    }
    __syncthreads();

    // ===== Phase M: per row-tile: W' -> S^T -> R (R kept in regs, packed bf16) =====
    {
      const uint16_t* Ql = Qtg + layer * 16384;
      #pragma unroll
      for (int ti = 0; ti < 3; ++ti) {
        if (ti < ntile) {
          const int mt = (ti == 2) ? 16 : (w + ti * 8);
          const int mbase = mt * 16;

          short8 bz[4];  // Z rows of this m-tile (B operand of W'-GEMM)
          #pragma unroll
          for (int kk = 0; kk < 4; ++kk)
            bz[kk] = *(const short8*)(Zbf + (mbase + l15) * ZP + kk * 32 + g * 8);

          f32x4 sacc[16];
          #pragma unroll
          for (int t = 0; t < 16; ++t) sacc[t] = (f32x4){0.f, 0.f, 0.f, 0.f};

          #pragma unroll
          for (int c = 0; c < 2; ++c) {   // d-chunks of 64
            // W'[d][m] = sum_k Qt[d][k] Z[m][k]; write W[m][d] chunk to scratch
            #pragma unroll
            for (int dt = 0; dt < 4; ++dt) {
              const int d0 = 64 * c + 16 * dt;
              f32x4 wa = {0.f, 0.f, 0.f, 0.f};
              #pragma unroll
              for (int kk = 0; kk < 4; ++kk) {
                short8 aq = *(const short8*)(Ql + (d0 + l15) * 128 + kk * 32 + g * 8);
                wa = MFMA16(aq, bz[kk], wa);
              }
              uint32_t* dst = (uint32_t*)(scr + l15 * SCRP + 16 * dt + 4 * g);
              dst[0] = pk2(wa[0], wa[1]);
              dst[1] = pk2(wa[2], wa[3]);
            }
            // S^T[tok][m] += sum_d Z[tok][d] W[m][d]
            short8 bw[2];
            #pragma unroll
            for (int kk2 = 0; kk2 < 2; ++kk2)
              bw[kk2] = *(const short8*)(scr + l15 * SCRP + 32 * kk2 + 8 * g);
            #pragma unroll
            for (int t = 0; t < 16; ++t) {
              #pragma unroll
              for (int kk2 = 0; kk2 < 2; ++kk2) {
                short8 az = *(const short8*)(Zbf + (16 * t + l15) * ZP + 64 * c + 32 * kk2 + 8 * g);
                sacc[t] = MFMA16(az, bw[kk2], sacc[t]);
              }
            }
          }

          // GEMV: R[m][128] = sum_tok S^T[tok][m] * zbar[tok] / 256
          float r128 = 0.f;
          #pragma unroll
          for (int t = 0; t < 16; ++t) {
            f32x4 z4 = *(const f32x4*)(zbar + 16 * t + 4 * g);
            r128 += sacc[t][0] * z4[0] + sacc[t][1] * z4[1] +
                    sacc[t][2] * z4[2] + sacc[t][3] * z4[3];
          }
          r128 += __shfl_xor(r128, 16);
          r128 += __shfl_xor(r128, 32);
          ts[ti].r128 = r128 * inv_n;

          // R[m][i] = sum_tok S[m][tok] key[tok][i] / 256
          f32x4 racc[8];
          #pragma unroll
          for (int it = 0; it < 8; ++it) racc[it] = (f32x4){0.f, 0.f, 0.f, 0.f};
          #pragma unroll
          for (int s = 0; s < 4; ++s) {   // tok-chunks of 64
            #pragma unroll
            for (int tt = 0; tt < 4; ++tt) {   // pack S^T tiles 4s..4s+3 -> scratch S[m][tok]
              f32x4 v = sacc[4 * s + tt];
              uint32_t* dst = (uint32_t*)(scr + l15 * SCRP + 16 * tt + 4 * g);
              dst[0] = pk2(v[0], v[1]);
              dst[1] = pk2(v[2], v[3]);
            }
            #pragma unroll
            for (int kk2 = 0; kk2 < 2; ++kk2) {
              short8 as = *(const short8*)(scr + l15 * SCRP + 32 * kk2 + 8 * g);
              #pragma unroll
              for (int it = 0; it < 8; ++it) {
                short8 bkey = *(const short8*)(keyT + (16 * it + l15) * KP + 64 * s + 32 * kk2 + 8 * g);
                racc[it] = MFMA16(as, bkey, racc[it]);
              }
            }
          }
          #pragma unroll
          for (int it = 0; it < 8; ++it) {
            ts[ti].rpk[2 * it]     = pk2(racc[it][0] * inv_n, racc[it][1] * inv_n);
            ts[ti].rpk[2 * it + 1] = pk2(racc[it][2] * inv_n, racc[it][3] * inv_n);
          }
        }
      }
    }
    __syncthreads();

    // ===== Phase U: Z += R + acc; acc += R*gamma; refresh Zbf/zbar =====
    {
      const float* Zsrc = (layer == 0) ? Zb_in : Zb_out;
      const float* gml  = gamma + layer * 33153;
      #pragma unroll
      for (int ti = 0; ti < 3; ++ti) {
        if (ti < ntile) {
          const int mt = (ti == 2) ? 16 : (w + ti * 8);
          const int mbase = mt * 16;
          #pragma unroll
          for (int it = 0; it < 8; ++it) {
            const int i = 16 * it + l15;   // < 128 always
            float an[4];
            #pragma unroll
            for (int r = 0; r < 4; ++r) {
              const int m = mbase + 4 * g + r;
              uint32_t pw = ts[ti].rpk[2 * it + (r >> 1)];
              float Rv = (r & 1) ? bfhi(pw) : bflo(pw);
              float ao = 0.f;
              if (layer > 0) {
                uint32_t aw = ts[ti].apk[2 * it + (r >> 1)];
                ao = (r & 1) ? bfhi(aw) : bflo(aw);
              }
              float zo = 0.f, ga = 0.f;
              if (m < 257) { zo = Zsrc[m * 129 + i]; ga = gml[m * 129 + i]; }
              float zn = zo + Rv + ao;
              if (m < 257) {
                Zb_out[m * 129 + i] = zn;
                Zbf[m * ZP + i] = f2bf(zn);
              }
              an[r] = ao + Rv * ga;
            }
            ts[ti].apk[2 * it]     = pk2(an[0], an[1]);
            ts[ti].apk[2 * it + 1] = pk2(an[2], an[3]);
          }
          // column 128
          if (lane < 16) {
            const int m = mbase + l15;
            if (m < 257) {
              float Rv = ts[ti].r128;
              float ao = (layer > 0) ? ts[ti].a128 : 0.f;
              float zn = Zsrc[m * 129 + 128] + Rv + ao;
              Zb_out[m * 129 + 128] = zn;
              zbar[m] = zn;
              ts[ti].a128 = ao + Rv * gml[m * 129 + 128];
            }
          }
        }
      }
    }
  }
}

// Convert allparam (f32) -> bf16: Pg[l][i][d] = P[i][d] (row-major),
// Qtg[l][n][k] = Q[k][n] (transposed).
__global__ void prep_params(const float* __restrict__ ap,
                            uint16_t* __restrict__ qtg, uint16_t* __restrict__ pg)
{
  int t = blockIdx.x * 256 + threadIdx.x;   // 0..65535
  int l = t >> 14, rem = t & 16383, i = rem >> 7, j = rem & 127;
  pg[t]  = f2bf(ap[((l * 2 + 0) * 128 + i) * 128 + j]);
  qtg[t] = f2bf(ap[((l * 2 + 1) * 128 + j) * 128 + i]);
}

extern "C" void kernel_launch(void* const* d_in, const int* in_sizes, int n_in,
                              void* d_out, int out_size, void* d_ws, size_t ws_size,
                              hipStream_t stream)
{
  const float* Z  = (const float*)d_in[0];
  const float* ap = (const float*)d_in[1];
  const float* gm = (const float*)d_in[2];

  uint16_t* qtg = (uint16_t*)d_ws;            // 4*128*128 bf16
  uint16_t* pg  = qtg + 4 * 128 * 128;        // 4*128*128 bf16  (total 256 KiB)

  (void)hipFuncSetAttribute((const void*)tf_layers,
                            hipFuncAttributeMaxDynamicSharedMemorySize, LDS_TOTAL);

  prep_params<<<256, 256, 0, stream>>>(ap, qtg, pg);
  tf_layers<<<512, 512, LDS_TOTAL, stream>>>(Z, gm, qtg, pg, (float*)d_out);
}

// Round 3
// 469.662 us; speedup vs baseline: 1.3068x; 1.3068x over previous
//
#include <hip/hip_runtime.h>
#include <hip/hip_bf16.h>
#include <stdint.h>

// B=512, N=256, D=128, 4 layers. One block (1024 thr, 16 waves) per batch.
// Wave w owns rows 16w..16w+15 across all layers: f32 master Z in registers
// (Zf[8][4], MFMA D-frag layout), acc as packed bf16 (apk). Col-128 master in
// LDS zbar (f32); row-256 handled by distributed VALU paths. Per layer:
//   K: keyT[i][tok] = (Z P^T)^T (bf16, token-contiguous) + W256 row
//   M: W = Z Q -> S^T = Z W^T -> GEMV (col 128) -> R = S keyT^T / n
//   U: Z += R + acc; acc += R*gamma (registers; global write only at layer 3)
// Fragment relayout between chained GEMMs uses per-wave LDS scratch
// (ds_write then same-wave ds_read; DS ops are in-order per wave — R1-proven).

using short8 = __attribute__((ext_vector_type(8))) short;
using f32x4  = __attribute__((ext_vector_type(4))) float;

#define MFMA16(A,B,C) __builtin_amdgcn_mfma_f32_16x16x32_bf16((A),(B),(C),0,0,0)

__device__ __forceinline__ uint16_t f2bf(float f) {
  union { __hip_bfloat16 h; uint16_t u; } cv; cv.h = __float2bfloat16(f); return cv.u;
}
__device__ __forceinline__ uint32_t pk2(float lo, float hi) {
  return (uint32_t)f2bf(lo) | ((uint32_t)f2bf(hi) << 16);
}
__device__ __forceinline__ float bflo(uint32_t p) { return __uint_as_float(p << 16); }
__device__ __forceinline__ float bfhi(uint32_t p) { return __uint_as_float(p & 0xffff0000u); }

// ---- LDS geometry (bytes); all tile row strides are multiples of 16 B ----
#define ZP        136                      // Zbf pitch elems (272 B rows)
#define KP        264                      // keyT pitch elems (528 B rows)
#define ZB_OFF    0
#define KT_OFF    (257*ZP*2)               // 69,904
#define ZBAR_OFF  (KT_OFF + 128*KP*2)      // 137,488
#define ZF256_OFF (ZBAR_OFF + 1040)        // 138,528
#define A256_OFF  (ZF256_OFF + 528)        // 139,056
#define W256_OFF  (A256_OFF + 528)         // 139,584
#define S256_OFF  (W256_OFF + 256)         // 139,840
#define P128_OFF  (S256_OFF + 512)         // 140,352
#define SCR_OFF   (P128_OFF + 64)          // 140,416
#define SCRP      40                       // scratch pitch elems (80 B rows)
#define LDS_TOTAL (SCR_OFF + 16*16*SCRP*2) // 160,896 <= 163,840

__global__ __launch_bounds__(1024)
void tf_layers(const float* __restrict__ Zin, const float* __restrict__ gamma,
               const uint16_t* __restrict__ Qtg, const uint16_t* __restrict__ Pg,
               float* __restrict__ Zout)
{
  extern __shared__ char lds[];
  uint16_t* Zbf   = (uint16_t*)(lds + ZB_OFF);   // [257][ZP] bf16, cols<128
  uint16_t* keyT  = (uint16_t*)(lds + KT_OFF);   // [128][KP] bf16, keyT[i][tok]
  float*    zbar  = (float*)(lds + ZBAR_OFF);    // [257] f32 master col 128
  float*    Zf256 = (float*)(lds + ZF256_OFF);   // [128] f32 master row 256
  float*    acc256= (float*)(lds + A256_OFF);    // [129] f32 acc row 256
  uint16_t* W256  = (uint16_t*)(lds + W256_OFF); // [128] bf16
  uint16_t* S256  = (uint16_t*)(lds + S256_OFF); // [256] bf16
  float*    p128  = (float*)(lds + P128_OFF);    // [16]  f32 partials

  const int tid = threadIdx.x, lane = tid & 63, w = tid >> 6;
  const int l15 = lane & 15, g = lane >> 4;
  const int b = blockIdx.x;
  const int mb = 16*w;
  const float inv_n = 1.0f/256.0f;

  uint16_t* scr = (uint16_t*)(lds + SCR_OFF) + w * 16 * SCRP;  // per-wave [16][SCRP]

  const float* Zb = Zin + (size_t)b*33153;   // 257*129
  float*       Zo = Zout + (size_t)b*33153;

  // ---- init ----
  for (int i2 = tid; i2 < 33153; i2 += 1024) {
    int r = i2/129, c = i2 - r*129;
    float v = Zb[i2];
    if (c < 128) Zbf[r*ZP + c] = f2bf(v); else zbar[r] = v;
  }
  if (tid < 128)  Zf256[tid] = Zb[256*129 + tid];
  if (tid <= 128) acc256[tid] = 0.0f;

  // f32 master rows for this wave (D-frag layout: row mb+4g+r, col 16it+l15)
  float Zf[8][4];
#pragma unroll
  for (int it = 0; it < 8; ++it)
#pragma unroll
    for (int r = 0; r < 4; ++r)
      Zf[it][r] = Zb[(mb + 4*g + r)*129 + 16*it + l15];

  uint32_t apk[16];
#pragma unroll
  for (int i = 0; i < 16; ++i) apk[i] = 0;
  float a128 = 0.0f;

#pragma unroll 1
  for (int l = 0; l < 4; ++l) {
    const uint16_t* Ql  = Qtg + l*16384;
    const uint16_t* Pl  = Pg  + l*16384;
    const float*    gml = gamma + l*33153;
    const bool last = (l == 3);

    __syncthreads();   // Zbf/zbar/Zf256 stable (init or previous U)

    // ===== K: keyT[i][tok] = sum_d Z[tok][d] P[i][d]; + W256 row =====
    {
      const int it8 = w >> 1, h = w & 1;
      const int irow = 16*it8 + l15;
      short8 bk[4];
#pragma unroll
      for (int kk = 0; kk < 4; ++kk)
        bk[kk] = *(const short8*)(Pl + irow*128 + kk*32 + g*8);
#pragma unroll
      for (int t = 0; t < 8; ++t) {
        const int tt = 8*h + t;
        f32x4 a4 = {0,0,0,0};
#pragma unroll
        for (int kk = 0; kk < 4; ++kk) {
          short8 az = *(const short8*)(Zbf + (16*tt + l15)*ZP + kk*32 + g*8);
          a4 = MFMA16(az, bk[kk], a4);
        }
        uint32_t* dst = (uint32_t*)(keyT + irow*KP + 16*tt + 4*g);
        dst[0] = pk2(a4[0], a4[1]); dst[1] = pk2(a4[2], a4[3]);
      }
      // W256[d] = dot(Qt[d], Z[256][:]) — 8 d per wave, 8 lanes per d
      {
        const int d = 8*w + (lane >> 3), ks = (lane & 7)*16;
        const uint32_t* qr = (const uint32_t*)(Ql + d*128 + ks);
        const uint32_t* zr = (const uint32_t*)(Zbf + 256*ZP + ks);
        float v = 0;
#pragma unroll
        for (int j = 0; j < 8; ++j) {
          uint32_t q_ = qr[j], z_ = zr[j];
          v += bflo(q_)*bflo(z_) + bfhi(q_)*bfhi(z_);
        }
        v += __shfl_xor(v,1); v += __shfl_xor(v,2); v += __shfl_xor(v,4);
        if ((lane & 7) == 0) W256[d] = f2bf(v);
      }
    }
    __syncthreads();   // keyT + W256 ready

    // ===== M: W -> S^T -> GEMV -> R for own 16-row tile; + S256 row =====
    uint32_t rpk[16];
    float r128 = 0.0f;
    {
      // S256[tok] for own 16 toks (4 lanes per tok) + p128 partial
      {
        const int tok = mb + (lane >> 2), ds0 = (lane & 3)*32;
        const uint32_t* wr = (const uint32_t*)(W256 + ds0);
        const uint32_t* zr = (const uint32_t*)(Zbf + tok*ZP + ds0);
        float v = 0;
#pragma unroll
        for (int j2 = 0; j2 < 16; ++j2) {
          uint32_t a_ = wr[j2], z_ = zr[j2];
          v += bflo(a_)*bflo(z_) + bfhi(a_)*bfhi(z_);
        }
        v += __shfl_xor(v,1); v += __shfl_xor(v,2);
        float pv = 0;
        if ((lane & 3) == 0) { S256[tok] = f2bf(v); pv = v * zbar[tok]; }
        pv += __shfl_xor(pv,1);  pv += __shfl_xor(pv,2);  pv += __shfl_xor(pv,4);
        pv += __shfl_xor(pv,8);  pv += __shfl_xor(pv,16); pv += __shfl_xor(pv,32);
        if (lane == 0) p128[w] = pv;
      }

      // W[m][d] = sum_k Z[m][k] Qt[d][k]: 4 chunks of 32 d, scratch relayout
      short8 bw[4];
      {
        short8 bz[4];
#pragma unroll
        for (int kk = 0; kk < 4; ++kk)
          bz[kk] = *(const short8*)(Zbf + (mb + l15)*ZP + kk*32 + g*8);
#pragma unroll
        for (int q32 = 0; q32 < 4; ++q32) {
#pragma unroll
          for (int hf = 0; hf < 2; ++hf) {          // d-tile dt = 2*q32 + hf
            const int dt = 2*q32 + hf;
            f32x4 t4 = {0,0,0,0};
#pragma unroll
            for (int kk = 0; kk < 4; ++kk) {
              short8 aq = *(const short8*)(Ql + (16*dt + l15)*128 + kk*32 + g*8);
              t4 = MFMA16(aq, bz[kk], t4);
            }
            // D: col=m=l15, rows d = 16dt + 4g + r -> scr[m][16hf+4g+r]
            uint32_t* dst = (uint32_t*)(scr + l15*SCRP + 16*hf + 4*g);
            dst[0] = pk2(t4[0], t4[1]); dst[1] = pk2(t4[2], t4[3]);
          }
          bw[q32] = *(const short8*)(scr + l15*SCRP + g*8);  // same-wave RAW
        }
      }

      // S^T -> GEMV -> R, fused per 64-token chunk
      f32x4 racc[8];
#pragma unroll
      for (int it = 0; it < 8; ++it) racc[it] = (f32x4){0,0,0,0};
#pragma unroll
      for (int p = 0; p < 4; ++p) {
        f32x4 sacc[4];
#pragma unroll
        for (int t = 0; t < 4; ++t) sacc[t] = (f32x4){0,0,0,0};
#pragma unroll
        for (int t = 0; t < 4; ++t)
#pragma unroll
          for (int q = 0; q < 4; ++q) {
            short8 az = *(const short8*)(Zbf + (64*p + 16*t + l15)*ZP + q*32 + g*8);
            sacc[t] = MFMA16(az, bw[q], sacc[t]);
          }
#pragma unroll
        for (int t = 0; t < 4; ++t) {
          f32x4 z4 = *(const f32x4*)(zbar + 64*p + 16*t + 4*g);
          r128 += sacc[t][0]*z4[0] + sacc[t][1]*z4[1]
                + sacc[t][2]*z4[2] + sacc[t][3]*z4[3];
        }
        // relayout 2 halves of 32 toks; R MFMAs immediately
#pragma unroll
        for (int hf = 0; hf < 2; ++hf) {
#pragma unroll
          for (int tt = 0; tt < 2; ++tt) {
            f32x4 v = sacc[2*hf + tt];
            uint32_t* dst = (uint32_t*)(scr + l15*SCRP + 16*tt + 4*g);
            dst[0] = pk2(v[0], v[1]); dst[1] = pk2(v[2], v[3]);
          }
          short8 sA = *(const short8*)(scr + l15*SCRP + g*8);  // same-wave RAW
#pragma unroll
          for (int it = 0; it < 8; ++it) {
            short8 bkey = *(const short8*)(keyT + (16*it + l15)*KP + 64*p + 32*hf + 8*g);
            racc[it] = MFMA16(sA, bkey, racc[it]);
          }
        }
      }
      r128 += __shfl_xor(r128, 16);
      r128 += __shfl_xor(r128, 32);
      r128 *= inv_n;
#pragma unroll
      for (int it = 0; it < 8; ++it) {
        rpk[2*it]   = pk2(racc[it][0]*inv_n, racc[it][1]*inv_n);
        rpk[2*it+1] = pk2(racc[it][2]*inv_n, racc[it][3]*inv_n);
      }
    }
    __syncthreads();   // all M reads of Zbf/zbar done; S256/p128 ready

    // ===== U: Z += R + acc; acc += R*gamma; refresh Zbf/zbar; + row 256 =====
    {
#pragma unroll
      for (int it = 0; it < 8; ++it) {
        const int col = 16*it + l15;
        float R[4] = {bflo(rpk[2*it]), bfhi(rpk[2*it]),
                      bflo(rpk[2*it+1]), bfhi(rpk[2*it+1])};
        float A[4] = {bflo(apk[2*it]), bfhi(apk[2*it]),
                      bflo(apk[2*it+1]), bfhi(apk[2*it+1])};
#pragma unroll
        for (int r = 0; r < 4; ++r) {
          const int m = mb + 4*g + r;
          float ga = gml[m*129 + col];
          float zf = Zf[it][r] + R[r] + A[r];
          Zf[it][r] = zf;
          A[r] = A[r] + R[r]*ga;
          Zbf[m*ZP + col] = f2bf(zf);
          if (last) Zo[m*129 + col] = zf;
        }
        apk[2*it]   = pk2(A[0], A[1]);
        apk[2*it+1] = pk2(A[2], A[3]);
      }
      if (lane < 16) {
        const int m = mb + l15;
        float zo = zbar[m], ga = gml[m*129 + 128];
        float zn = zo + r128 + a128;
        zbar[m] = zn;
        a128 = a128 + r128*ga;
        if (last) Zo[m*129 + 128] = zn;
      }
      // row 256: R256[i] = dot(S256, keyT[i]) / n — 8 i per wave
      {
        const int i = 8*w + (lane >> 3), ts0 = (lane & 7)*32;
        const uint32_t* sr = (const uint32_t*)(S256 + ts0);
        const uint32_t* kr = (const uint32_t*)(keyT + i*KP + ts0);
        float v = 0;
#pragma unroll
        for (int j2 = 0; j2 < 16; ++j2) {
          uint32_t s_ = sr[j2], k_ = kr[j2];
          v += bflo(s_)*bflo(k_) + bfhi(s_)*bfhi(k_);
        }
        v += __shfl_xor(v,1); v += __shfl_xor(v,2); v += __shfl_xor(v,4);
        if ((lane & 7) == 0) {
          float R = v*inv_n;
          float zo = Zf256[i], ao = acc256[i], ga = gml[256*129 + i];
          float zn = zo + R + ao;
          Zf256[i] = zn;
          acc256[i] = ao + R*ga;
          Zbf[256*ZP + i] = f2bf(zn);
          if (last) Zo[256*129 + i] = zn;
        }
        if (w == 15 && lane == 0) {
          float s = 0;
#pragma unroll
          for (int k = 0; k < 16; ++k) s += p128[k];
          float R = s*inv_n;
          float ga = gml[256*129 + 128];
          float zn = zbar[256] + R + acc256[128];
          zbar[256] = zn;
          acc256[128] = acc256[128] + R*ga;
          if (last) Zo[256*129 + 128] = zn;
        }
      }
    }
  }
}

// allparam f32 -> bf16: Pg[l][i][d] = P[i][d]; Qtg[l][d][k] = Q[k][d].
__global__ void prep_params(const float* __restrict__ ap,
                            uint16_t* __restrict__ qtg, uint16_t* __restrict__ pg)
{
  int t = blockIdx.x * 256 + threadIdx.x;   // 0..65535
  int l = t >> 14, rem = t & 16383, i = rem >> 7, j = rem & 127;
  pg[t]  = f2bf(ap[((l*2 + 0)*128 + i)*128 + j]);
  qtg[t] = f2bf(ap[((l*2 + 1)*128 + j)*128 + i]);
}

extern "C" void kernel_launch(void* const* d_in, const int* in_sizes, int n_in,
                              void* d_out, int out_size, void* d_ws, size_t ws_size,
                              hipStream_t stream)
{
  const float* Z  = (const float*)d_in[0];
  const float* ap = (const float*)d_in[1];
  const float* gm = (const float*)d_in[2];

  uint16_t* qtg = (uint16_t*)d_ws;            // 4*128*128 bf16
  uint16_t* pg  = qtg + 4*128*128;            // 4*128*128 bf16 (256 KiB total)

  (void)hipFuncSetAttribute((const void*)tf_layers,
                            hipFuncAttributeMaxDynamicSharedMemorySize, LDS_TOTAL);

  prep_params<<<256, 256, 0, stream>>>(ap, qtg, pg);
  tf_layers<<<512, 1024, LDS_TOTAL, stream>>>(Z, gm, qtg, pg, (float*)d_out);
}